// Round 8
// baseline (79.288 us; speedup 1.0000x reference)
//
#include <hip/hip_runtime.h>
#include <hip/hip_bf16.h>

typedef __attribute__((ext_vector_type(8))) short short8;   // bf16x8 MFMA frag
typedef __attribute__((ext_vector_type(4))) float f32x4;
typedef __attribute__((ext_vector_type(2))) float f32x2;
typedef __attribute__((ext_vector_type(4))) unsigned uint4v;

constexpr int N1 = 16384, N2 = 8192, N3 = 4096;
constexpr int WN = 36864;
constexpr float ISQ3 = 0.57735026918962576451f;

__device__ __forceinline__ unsigned short f2bf(float f) {
  unsigned u = __builtin_bit_cast(unsigned, f);
  u += 0x7fffu + ((u >> 16) & 1u);   // RNE
  return (unsigned short)(u >> 16);
}

// packed RNE f32x2 -> bf16x2 (single HW instruction)
__device__ __forceinline__ unsigned pkbf(float a, float b) {
  unsigned r;
  asm("v_cvt_pk_bf16_f32 %0, %1, %2" : "=v"(r) : "v"(a), "v"(b));
  return r;
}

#define MFMA(a, b, c) __builtin_amdgcn_mfma_f32_16x16x32_bf16((a), (b), (c), 0, 0, 0)

// scale 8 f32x2 pairs by S, pack into two bf16x8 frags (kh0: HA[0..3], kh1: HA[4..7])
#define SYNTH2(S, HA, G0, G1) do {                                            \
    f32x2 sv_; sv_[0] = (S); sv_[1] = (S);                                    \
    uint4v w0_, w1_;                                                          \
    f32x2 p0_ = sv_ * HA[0], p1_ = sv_ * HA[1], p2_ = sv_ * HA[2], p3_ = sv_ * HA[3]; \
    w0_[0] = pkbf(p0_[0], p0_[1]); w0_[1] = pkbf(p1_[0], p1_[1]);             \
    w0_[2] = pkbf(p2_[0], p2_[1]); w0_[3] = pkbf(p3_[0], p3_[1]);             \
    f32x2 p4_ = sv_ * HA[4], p5_ = sv_ * HA[5], p6_ = sv_ * HA[6], p7_ = sv_ * HA[7]; \
    w1_[0] = pkbf(p4_[0], p4_[1]); w1_[1] = pkbf(p5_[0], p5_[1]);             \
    w1_[2] = pkbf(p6_[0], p6_[1]); w1_[3] = pkbf(p7_[0], p7_[1]);             \
    G0 = __builtin_bit_cast(short8, w0_); G1 = __builtin_bit_cast(short8, w1_); \
  } while (0)

// convert two f32x4 to one bf16x8 frag
#define CVT8(X0, X1, G) do { uint4v w_;                                       \
    w_[0] = pkbf(X0[0], X0[1]); w_[1] = pkbf(X0[2], X0[3]);                   \
    w_[2] = pkbf(X1[0], X1[1]); w_[3] = pkbf(X1[2], X1[3]);                   \
    G = __builtin_bit_cast(short8, w_); } while (0)

// ---------------- fused prep (one launch):
// [0,512): init_out (b2 part + bias)    [512,1664): W2 -> Bp permute
// [1664,2688): MLP -> H                 [2688,2816): scale buffers
__global__ __launch_bounds__(256)
void k_prep(const float* __restrict__ wgt, const float* __restrict__ W0,
            const float* __restrict__ b0, const float* __restrict__ W1,
            const float* __restrict__ b1, const float* __restrict__ W2,
            const float* __restrict__ b2, const float* __restrict__ bias,
            const float* __restrict__ d1, const float* __restrict__ d2,
            float* __restrict__ H, unsigned short* __restrict__ Bp,
            float* __restrict__ sBg, float* __restrict__ sDg,
            float* __restrict__ sCg, float* __restrict__ d2T,
            float* __restrict__ out) {
  __shared__ __align__(16) float shm[10400];
  const int bid = blockIdx.x;
  const int tid = threadIdx.x;

  if (bid < 512) {
    float* s1s = shm;            // [8][128]
    float* v1s = shm + 1024;     // [8][64][3]
    float* dts = shm + 2560;     // [8][64]
    float* s2s = shm + 3072;     // [8]
    float* v2s = shm + 3080;     // [8][3]
    const int e0 = bid * 8;
    for (int x = tid; x < 8 * 320; x += 256) {
      int e = x / 320, c = x % 320;
      float v = d1[(size_t)(e0 + e) * 320 + c];
      if (c < 128) s1s[e * 128 + c] = v;
      else { int q = c - 128; v1s[(e * 64 + q / 3) * 3 + q % 3] = v; }
    }
    if (tid < 32) {
      int e = tid >> 2, c = tid & 3;
      float v = d2[(size_t)(e0 + e) * 4 + c];
      if (c == 0) s2s[e] = v; else v2s[e * 3 + c - 1] = v;
    }
    __syncthreads();
    for (int x = tid; x < 8 * 64; x += 256) {
      int e = x >> 6, u = x & 63;
      dts[e * 64 + u] = v1s[(e * 64 + u) * 3] * v2s[e * 3] +
                        v1s[(e * 64 + u) * 3 + 1] * v2s[e * 3 + 1] +
                        v1s[(e * 64 + u) * 3 + 2] * v2s[e * 3 + 2];
    }
    __syncthreads();
    for (int c = tid; c < 320; c += 256) {
      if (c < 128) {
        const int w = c;
        float ta[8] = {0,0,0,0,0,0,0,0}, td[8] = {0,0,0,0,0,0,0,0};
        for (int u = 0; u < 128; ++u) {
          float bv = b2[u * 128 + w];
#pragma unroll
          for (int e = 0; e < 8; ++e) ta[e] = fmaf(s1s[e * 128 + u], bv, ta[e]);
        }
        for (int u = 0; u < 64; ++u) {
          float bv = b2[N1 + N2 + N3 + u * 128 + w];
#pragma unroll
          for (int e = 0; e < 8; ++e) td[e] = fmaf(dts[e * 64 + u], bv, td[e]);
        }
        const float bw = bias[w];
#pragma unroll
        for (int e = 0; e < 8; ++e)
          out[(size_t)(e0 + e) * 320 + c] = fmaf(s2s[e], ta[e], ISQ3 * td[e]) + bw;
      } else {
        const int q = c - 128, w = q / 3, i = q % 3;
        float tb[8] = {0,0,0,0,0,0,0,0}, tc[8] = {0,0,0,0,0,0,0,0};
        for (int u = 0; u < 128; ++u) {
          float bv = b2[N1 + u * 64 + w];
#pragma unroll
          for (int e = 0; e < 8; ++e) tb[e] = fmaf(s1s[e * 128 + u], bv, tb[e]);
        }
        for (int u = 0; u < 64; ++u) {
          float bv = b2[N1 + N2 + u * 64 + w];
#pragma unroll
          for (int e = 0; e < 8; ++e) tc[e] = fmaf(v1s[(e * 64 + u) * 3 + i], bv, tc[e]);
        }
#pragma unroll
        for (int e = 0; e < 8; ++e)
          out[(size_t)(e0 + e) * 320 + c] = tb[e] * v2s[e * 3 + i] + tc[e] * s2s[e];
      }
    }
  } else if (bid < 1664) {
    const int g = (bid - 512) * 256 + tid;
    const int lane = g & 63;
    const int nth = g >> 6;
    const int kh = nth & 1, nt = nth >> 1;
    const int n = nt * 16 + (lane & 15);
    const int k0 = kh * 32 + (lane >> 4) * 8;
    short8 v;
#pragma unroll
    for (int q = 0; q < 8; ++q) v[q] = (short)f2bf(W2[(size_t)(k0 + q) * WN + n]);
    *(short8*)(Bp + (size_t)g * 8) = v;
  } else if (bid < 2688) {
    float* h0s = shm;
    const int r = tid >> 6, jj = tid & 63;
    const int e = (bid - 1664) * 4 + r;
    float a = b0[jj];
#pragma unroll
    for (int i = 0; i < 16; ++i) a = fmaf(wgt[e * 16 + i], W0[i * 64 + jj], a);
    h0s[r * 64 + jj] = fmaxf(a, 0.f);
    __syncthreads();
    float a1 = b1[jj];
#pragma unroll
    for (int i = 0; i < 64; ++i) a1 = fmaf(h0s[r * 64 + i], W1[i * 64 + jj], a1);
    H[e * 64 + jj] = fmaxf(a1, 0.f);
  } else {
    // scale buffers: sBg[u][e]=s1, sDg[u][e]=ISQ3*dot12, sCg[3u+i][e]=v1_i*s2, d2T
    float* d1s = shm;            // [32][321]
    float* d2s = shm + 10272;    // [32][4]
    const int e0 = (bid - 2688) * 32;
    for (int x = tid; x < 32 * 320; x += 256) {
      int e = x / 320, c = x % 320;
      d1s[e * 321 + c] = d1[(size_t)(e0 + e) * 320 + c];
    }
    if (tid < 128) d2s[tid] = d2[(size_t)e0 * 4 + tid];
    __syncthreads();
    const int e = tid & 31;
    const float s2 = d2s[e * 4 + 0];
    const float w1 = d2s[e * 4 + 1], w2 = d2s[e * 4 + 2], w3 = d2s[e * 4 + 3];
    for (int row = 128 + (tid >> 5); row < 516; row += 8) {
      float v; float* dst;
      if (row < 256)      { v = d1s[e * 321 + (row - 128)];         dst = sBg + (size_t)(row - 128) * 4096; }
      else if (row < 320) { int u = row - 256;
        v = ISQ3 * (d1s[e * 321 + 128 + 3 * u] * w1 + d1s[e * 321 + 129 + 3 * u] * w2 +
                    d1s[e * 321 + 130 + 3 * u] * w3);               dst = sDg + (size_t)u * 4096; }
      else if (row < 512) { v = d1s[e * 321 + 128 + (row - 320)] * s2; dst = sCg + (size_t)(row - 320) * 4096; }
      else                { v = d2s[e * 4 + (row - 512)];           dst = d2T + (size_t)(row - 512) * 4096; }
      dst[e0 + e] = v;
    }
  }
}

// ---------------- k_ab: A+B parts. 512 blocks = 128 e-tiles x 4 j-quarters (jq = xcd&3) ----------------
// acc: A 4 f32x4 + B 2 f32x4. One SYNTH(s1) per u serves both; s2 applied in epilogue (A only).
__global__ __launch_bounds__(512, 2)
void k_ab(const float* __restrict__ sBg, const float* __restrict__ d2T,
          const float* __restrict__ H, const unsigned short* __restrict__ Bp,
          float* __restrict__ out) {
  __shared__ float buf[4][32][49];   // 25 KB
  const int tid = threadIdx.x;
  const int wid = tid >> 6, lane = tid & 63;
  const int nl = lane & 15, grp = lane >> 4;
  const int xcd = blockIdx.x & 7;
  const int jq = xcd & 3;
  const int et = (int)(blockIdx.x >> 3) | ((xcd >> 2) << 6);
  const int e0 = et * 32;
  const short8* Bp8 = (const short8*)Bp;
  const f32x4 Zv = {0.f, 0.f, 0.f, 0.f};

  // H rows as f32x2 pairs (SYNTH inputs): k = grp*8+q (kh0), 32+grp*8+q (kh1)
  f32x2 hf0[8], hf1[8];
  {
    const float* hp0 = H + (size_t)(e0 + nl) * 64 + grp * 8;
    const float* hp1 = H + (size_t)(e0 + 16 + nl) * 64 + grp * 8;
    f32x4 x0 = *(const f32x4*)(hp0),      x1 = *(const f32x4*)(hp0 + 4);
    f32x4 x2 = *(const f32x4*)(hp0 + 32), x3 = *(const f32x4*)(hp0 + 36);
    f32x4 y0 = *(const f32x4*)(hp1),      y1 = *(const f32x4*)(hp1 + 4);
    f32x4 y2 = *(const f32x4*)(hp1 + 32), y3 = *(const f32x4*)(hp1 + 36);
    hf0[0][0]=x0[0]; hf0[0][1]=x0[1]; hf0[1][0]=x0[2]; hf0[1][1]=x0[3];
    hf0[2][0]=x1[0]; hf0[2][1]=x1[1]; hf0[3][0]=x1[2]; hf0[3][1]=x1[3];
    hf0[4][0]=x2[0]; hf0[4][1]=x2[1]; hf0[5][0]=x2[2]; hf0[5][1]=x2[3];
    hf0[6][0]=x3[0]; hf0[6][1]=x3[1]; hf0[7][0]=x3[2]; hf0[7][1]=x3[3];
    hf1[0][0]=y0[0]; hf1[0][1]=y0[1]; hf1[1][0]=y0[2]; hf1[1][1]=y0[3];
    hf1[2][0]=y1[0]; hf1[2][1]=y1[1]; hf1[3][0]=y1[2]; hf1[3][1]=y1[3];
    hf1[4][0]=y2[0]; hf1[4][1]=y2[1]; hf1[5][0]=y2[2]; hf1[5][1]=y2[3];
    hf1[6][0]=y3[0]; hf1[6][1]=y3[1]; hf1[7][0]=y3[2]; hf1[7][1]=y3[3];
  }

  f32x4 accA00 = Zv, accA01 = Zv, accA10 = Zv, accA11 = Zv;
  f32x4 accB0 = Zv, accB1 = Zv;

  const int u0 = wid * 16;
  const short8* pa = Bp8 + ((size_t)u0 * 8 + jq * 2) * 128 + lane;          // +1024/u
  const short8* pb = Bp8 + ((size_t)(1024 + u0 * 4 + jq)) * 128 + lane;     // +512/u
  const float* sb0 = sBg + (size_t)u0 * 4096 + e0 + nl;                     // +4096/u
  const float* sb1 = sb0 + 16;

#pragma unroll 4
  for (int ul = 0; ul < 16; ++ul) {
    short8 F00 = pa[0], F01 = pa[64], F10 = pa[128], F11 = pa[192];
    short8 G0 = pb[0], G1 = pb[64];
    float s0 = sb0[0], s1v = sb1[0];
    pa += 1024; pb += 512; sb0 += 4096; sb1 += 4096;
    short8 g00, g01, g10, g11;
    SYNTH2(s0, hf0, g00, g01);
    SYNTH2(s1v, hf1, g10, g11);
    accA00 = MFMA(F01, g01, MFMA(F00, g00, accA00));
    accA01 = MFMA(F01, g11, MFMA(F00, g10, accA01));
    accA10 = MFMA(F11, g01, MFMA(F10, g00, accA10));
    accA11 = MFMA(F11, g11, MFMA(F10, g10, accA11));
    accB0  = MFMA(G1,  g01, MFMA(G0,  g00, accB0));
    accB1  = MFMA(G1,  g11, MFMA(G0,  g10, accB1));
  }

  // ---- epilogue: 8->4 wave reduce, 4-sum, out += ----
  const int s = wid & 3;
  if (wid >= 4) {
#pragma unroll
    for (int r = 0; r < 4; ++r) {
      buf[s][nl][grp * 4 + r]           = accA00[r];
      buf[s][nl][16 + grp * 4 + r]      = accA10[r];
      buf[s][16 + nl][grp * 4 + r]      = accA01[r];
      buf[s][16 + nl][16 + grp * 4 + r] = accA11[r];
      buf[s][nl][32 + grp * 4 + r]      = accB0[r];
      buf[s][16 + nl][32 + grp * 4 + r] = accB1[r];
    }
  }
  __syncthreads();
  if (wid < 4) {
#pragma unroll
    for (int r = 0; r < 4; ++r) {
      buf[s][nl][grp * 4 + r]           += accA00[r];
      buf[s][nl][16 + grp * 4 + r]      += accA10[r];
      buf[s][16 + nl][grp * 4 + r]      += accA01[r];
      buf[s][16 + nl][16 + grp * 4 + r] += accA11[r];
      buf[s][nl][32 + grp * 4 + r]      += accB0[r];
      buf[s][16 + nl][32 + grp * 4 + r] += accB1[r];
    }
  }
  __syncthreads();
#pragma unroll
  for (int it = 0; it < 3; ++it) {
    const int p = tid + it * 512;
    const int e = p / 48, c = p % 48;
    float v = buf[0][e][c] + buf[1][e][c] + buf[2][e][c] + buf[3][e][c];
    float* orow = out + (size_t)(e0 + e) * 320;
    if (c < 32) {
      orow[jq * 32 + c] += d2T[e0 + e] * v;
    } else {
      const int q = c - 32;
      float* op = orow + 128 + (size_t)(jq * 16 + q) * 3;
      op[0] += v * d2T[4096 + e0 + e];
      op[1] += v * d2T[8192 + e0 + e];
      op[2] += v * d2T[12288 + e0 + e];
    }
  }
}

// ---------------- k_dc: D+C parts. 512 blocks = 128 e-tiles x 4 j-quarters. t-temp form ----------------
__global__ __launch_bounds__(512, 2)
void k_dc(const float* __restrict__ sDg, const float* __restrict__ sCg,
          const float* __restrict__ H, const unsigned short* __restrict__ Bp,
          float* __restrict__ out) {
  __shared__ float buf[4][32][81];   // 41.5 KB
  const int tid = threadIdx.x;
  const int wid = tid >> 6, lane = tid & 63;
  const int nl = lane & 15, grp = lane >> 4;
  const int xcd = blockIdx.x & 7;
  const int jq = xcd & 3;
  const int et = (int)(blockIdx.x >> 3) | ((xcd >> 2) << 6);
  const int e0 = et * 32;
  const short8* Bp8 = (const short8*)Bp;
  const f32x4 Zv = {0.f, 0.f, 0.f, 0.f};

  // unscaled H bf16 frags
  short8 hb00, hb01, hb10, hb11;
  {
    const float* hp0 = H + (size_t)(e0 + nl) * 64 + grp * 8;
    const float* hp1 = H + (size_t)(e0 + 16 + nl) * 64 + grp * 8;
    f32x4 x0 = *(const f32x4*)(hp0),      x1 = *(const f32x4*)(hp0 + 4);
    f32x4 x2 = *(const f32x4*)(hp0 + 32), x3 = *(const f32x4*)(hp0 + 36);
    f32x4 y0 = *(const f32x4*)(hp1),      y1 = *(const f32x4*)(hp1 + 4);
    f32x4 y2 = *(const f32x4*)(hp1 + 32), y3 = *(const f32x4*)(hp1 + 36);
    CVT8(x0, x1, hb00); CVT8(x2, x3, hb01);
    CVT8(y0, y1, hb10); CVT8(y2, y3, hb11);
  }

  f32x4 accD00 = Zv, accD01 = Zv, accD10 = Zv, accD11 = Zv;
  f32x4 accC00 = Zv, accC01 = Zv, accC02 = Zv;   // eF0, i=0..2
  f32x4 accC10 = Zv, accC11 = Zv, accC12 = Zv;   // eF1

  const int u0 = wid * 8;
  const short8* pd = Bp8 + ((size_t)(1792 + u0 * 8 + jq * 2)) * 128 + lane;  // +1024/u
  const short8* pc = Bp8 + ((size_t)(1536 + u0 * 4 + jq)) * 128 + lane;      // +512/u
  const float* sd0 = sDg + (size_t)u0 * 4096 + e0 + nl;                      // +4096/u
  const float* sc0 = sCg + (size_t)(3 * u0) * 4096 + e0 + nl;                // +12288/u

#pragma unroll 4
  for (int ul = 0; ul < 8; ++ul) {
    short8 FD00 = pd[0], FD01 = pd[64], FD10 = pd[128], FD11 = pd[192];
    short8 FC0 = pc[0], FC1 = pc[64];
    float sdE = sd0[0], sdO = sd0[16];
    float sc00 = sc0[0],          sc01 = sc0[16];
    float sc10 = sc0[4096],       sc11 = sc0[4096 + 16];
    float sc20 = sc0[8192],       sc21 = sc0[8192 + 16];
    pd += 1024; pc += 512; sd0 += 4096; sc0 += 12288;
    // D: unscaled chains then scale-accumulate
    f32x4 t00 = MFMA(FD01, hb01, MFMA(FD00, hb00, Zv));
    f32x4 t01 = MFMA(FD01, hb11, MFMA(FD00, hb10, Zv));
    f32x4 t10 = MFMA(FD11, hb01, MFMA(FD10, hb00, Zv));
    f32x4 t11 = MFMA(FD11, hb11, MFMA(FD10, hb10, Zv));
    accD00 += sdE * t00; accD01 += sdO * t01;
    accD10 += sdE * t10; accD11 += sdO * t11;
    // C: one chain per eF, 3 scale-accumulates each
    f32x4 tc0 = MFMA(FC1, hb01, MFMA(FC0, hb00, Zv));
    f32x4 tc1 = MFMA(FC1, hb11, MFMA(FC0, hb10, Zv));
    accC00 += sc00 * tc0; accC01 += sc10 * tc0; accC02 += sc20 * tc0;
    accC10 += sc01 * tc1; accC11 += sc11 * tc1; accC12 += sc21 * tc1;
  }

  // ---- epilogue ----
  const int s = wid & 3;
  if (wid >= 4) {
#pragma unroll
    for (int r = 0; r < 4; ++r) {
      buf[s][nl][grp * 4 + r]           = accD00[r];
      buf[s][nl][16 + grp * 4 + r]      = accD10[r];
      buf[s][16 + nl][grp * 4 + r]      = accD01[r];
      buf[s][16 + nl][16 + grp * 4 + r] = accD11[r];
      const int cb = 32 + (grp * 4 + r) * 3;
      buf[s][nl][cb]          = accC00[r];
      buf[s][nl][cb + 1]      = accC01[r];
      buf[s][nl][cb + 2]      = accC02[r];
      buf[s][16 + nl][cb]     = accC10[r];
      buf[s][16 + nl][cb + 1] = accC11[r];
      buf[s][16 + nl][cb + 2] = accC12[r];
    }
  }
  __syncthreads();
  if (wid < 4) {
#pragma unroll
    for (int r = 0; r < 4; ++r) {
      buf[s][nl][grp * 4 + r]           += accD00[r];
      buf[s][nl][16 + grp * 4 + r]      += accD10[r];
      buf[s][16 + nl][grp * 4 + r]      += accD01[r];
      buf[s][16 + nl][16 + grp * 4 + r] += accD11[r];
      const int cb = 32 + (grp * 4 + r) * 3;
      buf[s][nl][cb]          += accC00[r];
      buf[s][nl][cb + 1]      += accC01[r];
      buf[s][nl][cb + 2]      += accC02[r];
      buf[s][16 + nl][cb]     += accC10[r];
      buf[s][16 + nl][cb + 1] += accC11[r];
      buf[s][16 + nl][cb + 2] += accC12[r];
    }
  }
  __syncthreads();
#pragma unroll
  for (int it = 0; it < 5; ++it) {
    const int p = tid + it * 512;
    const int e = p / 80, c = p % 80;
    float v = buf[0][e][c] + buf[1][e][c] + buf[2][e][c] + buf[3][e][c];
    float* orow = out + (size_t)(e0 + e) * 320;
    if (c < 32) {
      orow[jq * 32 + c] += v;                       // D term (no s2; ISQ3 folded in sDg)
    } else {
      const int q = c - 32;                         // q in [0,48)
      const int w1l = q / 3, i = q - w1l * 3;
      orow[128 + (size_t)(jq * 16 + w1l) * 3 + i] += v;   // C term (s2 folded in sCg)
    }
  }
}

extern "C" void kernel_launch(void* const* d_in, const int* in_sizes, int n_in,
                              void* d_out, int out_size, void* d_ws, size_t ws_size,
                              hipStream_t stream) {
  const float* d1   = (const float*)d_in[0];
  const float* d2   = (const float*)d_in[1];
  const float* wgt  = (const float*)d_in[2];
  const float* W0   = (const float*)d_in[3];
  const float* b0   = (const float*)d_in[4];
  const float* W1   = (const float*)d_in[5];
  const float* b1   = (const float*)d_in[6];
  const float* W2   = (const float*)d_in[7];
  const float* b2   = (const float*)d_in[8];
  const float* bias = (const float*)d_in[9];
  float* out = (float*)d_out;

  char* ws = (char*)d_ws;
  float* H           = (float*)(ws);                         // 1 MiB
  unsigned short* Bp = (unsigned short*)(ws + (1u << 20));   // 4.72 MB
  float* sBg         = (float*)(ws + (8u << 20));            // 2 MB  [128][4096] s1
  float* sDg         = (float*)(ws + (10u << 20));           // 1 MB  [64][4096]  ISQ3*dot12
  float* sCg         = (float*)(ws + (11u << 20));           // 3 MB  [192][4096] v1_i*s2
  float* d2T         = (float*)(ws + (14u << 20));           // 64 KB [4][4096]

  k_prep<<<2816, 256, 0, stream>>>(wgt, W0, b0, W1, b1, W2, b2, bias, d1, d2,
                                   H, Bp, sBg, sDg, sCg, d2T, out);
  k_ab<<<512, 512, 0, stream>>>(sBg, d2T, H, Bp, out);
  k_dc<<<512, 512, 0, stream>>>(sDg, sCg, H, Bp, out);
}

// Round 10
// 68.610 us; speedup vs baseline: 1.1556x; 1.1556x over previous
//
#include <hip/hip_runtime.h>
#include <hip/hip_bf16.h>

typedef __attribute__((ext_vector_type(8))) short short8;   // bf16x8 MFMA frag
typedef __attribute__((ext_vector_type(4))) float f32x4;
typedef __attribute__((ext_vector_type(4))) unsigned uint4v;

constexpr int N1 = 16384, N2 = 8192, N3 = 4096;
constexpr int WN = 36864;
constexpr float ISQ3 = 0.57735026918962576451f;

__device__ __forceinline__ unsigned short f2bf(float f) {
  unsigned u = __builtin_bit_cast(unsigned, f);
  u += 0x7fffu + ((u >> 16) & 1u);   // RNE
  return (unsigned short)(u >> 16);
}

__device__ __forceinline__ unsigned pkbf(float a, float b) {
  unsigned r;
  asm("v_cvt_pk_bf16_f32 %0, %1, %2" : "=v"(r) : "v"(a), "v"(b));
  return r;
}

#define MFMA(a, b, c) __builtin_amdgcn_mfma_f32_16x16x32_bf16((a), (b), (c), 0, 0, 0)

// two f32x4 -> one bf16x8 frag
#define CVT8(X0, X1, G) do { uint4v w_;                                       \
    w_[0] = pkbf(X0[0], X0[1]); w_[1] = pkbf(X0[2], X0[3]);                   \
    w_[2] = pkbf(X1[0], X1[1]); w_[3] = pkbf(X1[2], X1[3]);                   \
    G = __builtin_bit_cast(short8, w_); } while (0)

// H frag loader: rows e0+16*EF+nl, k = grp*8.. (kh0) and 32+grp*8.. (kh1)
#define LOADH(EF, LO, HI) do {                                                \
    const float* hp_ = H + (size_t)(e0 + 16 * (EF) + nl) * 64 + grp * 8;      \
    f32x4 x0_ = *(const f32x4*)hp_,        x1_ = *(const f32x4*)(hp_ + 4);    \
    f32x4 x2_ = *(const f32x4*)(hp_ + 32), x3_ = *(const f32x4*)(hp_ + 36);   \
    CVT8(x0_, x1_, LO); CVT8(x2_, x3_, HI); } while (0)

// ---------------- prep: [0,288) W2->Bp (LDS transpose, coalesced) | [288,1312) MLP | [1312,1440) scales
__global__ __launch_bounds__(256)
void k_prep(const float* __restrict__ wgt, const float* __restrict__ W0,
            const float* __restrict__ b0, const float* __restrict__ W1,
            const float* __restrict__ b1, const float* __restrict__ W2,
            const float* __restrict__ d1, const float* __restrict__ d2,
            float* __restrict__ H, unsigned short* __restrict__ Bp,
            float* __restrict__ sBg, float* __restrict__ sDg,
            float* __restrict__ sCg, float* __restrict__ d2T) {
  __shared__ __align__(16) float shm[10400];
  const int bid = blockIdx.x;
  const int tid = threadIdx.x;

  if (bid < 288) {
    // ---- W2 -> Bp: block handles n-chunk [n0, n0+128), all 64 k-rows.
    const int n0 = bid * 128;
#pragma unroll
    for (int q = 0; q < 8; ++q) {
      const int flat = tid + q * 256;       // f32x4 units, 0..2047
      const int row = flat >> 5, c4 = flat & 31;
      *(f32x4*)&shm[row * 132 + c4 * 4] =
          *(const f32x4*)(W2 + (size_t)row * WN + n0 + c4 * 4);
    }
    __syncthreads();
#pragma unroll
    for (int q = 0; q < 4; ++q) {
      const int p = tid + q * 256;          // 0..1023
      const int ntl = p >> 7, kh = (p >> 6) & 1, lane2 = p & 63;
      const int k0 = kh * 32 + (lane2 >> 4) * 8;
      const int col = ntl * 16 + (lane2 & 15);
      short8 v;
#pragma unroll
      for (int qq = 0; qq < 8; ++qq) v[qq] = (short)f2bf(shm[(k0 + qq) * 132 + col]);
      *(short8*)(Bp + ((size_t)(n0 * 8 + p)) * 8) = v;
    }
  } else if (bid < 1312) {
    // ---- MLP: H = relu(relu(weight@W0+b0)@W1+b1)
    float* h0s = shm;
    const int r = tid >> 6, jj = tid & 63;
    const int e = (bid - 288) * 4 + r;
    float a = b0[jj];
#pragma unroll
    for (int i = 0; i < 16; ++i) a = fmaf(wgt[e * 16 + i], W0[i * 64 + jj], a);
    h0s[r * 64 + jj] = fmaxf(a, 0.f);
    __syncthreads();
    float a1 = b1[jj];
#pragma unroll
    for (int i = 0; i < 64; ++i) a1 = fmaf(h0s[r * 64 + i], W1[i * 64 + jj], a1);
    H[e * 64 + jj] = fmaxf(a1, 0.f);
  } else {
    // ---- scales: sBg[u][e]=s1, sDg[u][e]=ISQ3*dot12, sCg[3u+i][e]=v1_i*s2, d2T[c][e]
    float* d1s = shm;            // [32][321]
    float* d2s = shm + 10272;    // [32][4]
    const int e0 = (bid - 1312) * 32;
    for (int x = tid; x < 32 * 320; x += 256) {
      int e = x / 320, c = x % 320;
      d1s[e * 321 + c] = d1[(size_t)(e0 + e) * 320 + c];
    }
    if (tid < 128) d2s[tid] = d2[(size_t)e0 * 4 + tid];
    __syncthreads();
    const int e = tid & 31;
    const float s2 = d2s[e * 4 + 0];
    const float w1 = d2s[e * 4 + 1], w2 = d2s[e * 4 + 2], w3 = d2s[e * 4 + 3];
    for (int row = 128 + (tid >> 5); row < 516; row += 8) {
      float v; float* dst;
      if (row < 256)      { v = d1s[e * 321 + (row - 128)];            dst = sBg + (size_t)(row - 128) * 4096; }
      else if (row < 320) { int u = row - 256;
        v = ISQ3 * (d1s[e * 321 + 128 + 3 * u] * w1 + d1s[e * 321 + 129 + 3 * u] * w2 +
                    d1s[e * 321 + 130 + 3 * u] * w3);                  dst = sDg + (size_t)u * 4096; }
      else if (row < 512) { v = d1s[e * 321 + 128 + (row - 320)] * s2; dst = sCg + (size_t)(row - 320) * 4096; }
      else                { v = d2s[e * 4 + (row - 512)];              dst = d2T + (size_t)(row - 512) * 4096; }
      dst[e0 + e] = v;
    }
  }
}

// ---------------- k_main: exclusive-writer column decomposition, b2 via MFMA C-init ----------------
// bid [0,512): AD path — e-tile 64, j = bid&7 (XCD-pinned). Writes out0 cols [16j,16j+16).
// bid [512,1024): BC path — e-tile 32, jc = xcd&3. Writes out1 w1 cols [16jc,16jc+16) (x3 i).
__global__ __launch_bounds__(512, 4)
void k_main(const float* __restrict__ sBg, const float* __restrict__ sDg,
            const float* __restrict__ sCg, const float* __restrict__ d2T,
            const float* __restrict__ H, const unsigned short* __restrict__ Bp,
            const float* __restrict__ b2, const float* __restrict__ bias,
            float* __restrict__ out) {
  __shared__ __align__(16) float buf[8448];   // 33.8 KB: AD [4][64][33], BC [4][32][65]
  const int bid = blockIdx.x, tid = threadIdx.x;
  const int wid = tid >> 6, lane = tid & 63;
  const int nl = lane & 15, grp = lane >> 4;
  const short8* Bp8 = (const short8*)Bp;
  const f32x4 Zv = {0.f, 0.f, 0.f, 0.f};

  if (bid < 512) {
    // ================= AD =================
    const int j = bid & 7;
    const int e0 = (bid >> 3) * 64;
    short8 hL0, hH0, hL1, hH1, hL2, hH2, hL3, hH3;
    LOADH(0, hL0, hH0);
    LOADH(1, hL1, hH1);
    LOADH(2, hL2, hH2);
    LOADH(3, hL3, hH3);

    f32x4 aA0 = Zv, aA1 = Zv, aA2 = Zv, aA3 = Zv;
    f32x4 aD0 = Zv, aD1 = Zv, aD2 = Zv, aD3 = Zv;

    {   // phase A: u in [wid*16, +16), nt = u*8 + j
      const int u0 = wid * 16;
      const short8* pa = Bp8 + (size_t)(u0 * 8 + j) * 128 + lane;
      const float* sb = sBg + (size_t)u0 * 4096 + e0 + nl;
      const float* pb = b2 + (size_t)u0 * 128 + 16 * j + 4 * grp;
      short8 F0 = pa[0], F1 = pa[64];
      f32x4 bv = *(const f32x4*)pb;
      float s0 = sb[0], s1 = sb[16], s2 = sb[32], s3 = sb[48];
#pragma unroll
      for (int t = 0; t < 16; ++t) {
        short8 f0 = F0, f1 = F1; f32x4 b = bv;
        float c0 = s0, c1 = s1, c2 = s2, c3 = s3;
        if (t < 15) {
          pa += 1024; sb += 4096; pb += 128;
          F0 = pa[0]; F1 = pa[64]; bv = *(const f32x4*)pb;
          s0 = sb[0]; s1 = sb[16]; s2 = sb[32]; s3 = sb[48];
        }
        f32x4 tt;
        tt = MFMA(f0, hL0, b); tt = MFMA(f1, hH0, tt); aA0 += c0 * tt;
        tt = MFMA(f0, hL1, b); tt = MFMA(f1, hH1, tt); aA1 += c1 * tt;
        tt = MFMA(f0, hL2, b); tt = MFMA(f1, hH2, tt); aA2 += c2 * tt;
        tt = MFMA(f0, hL3, b); tt = MFMA(f1, hH3, tt); aA3 += c3 * tt;
      }
    }
    {   // phase D: u in [wid*8, +8), nt = 1792 + u*8 + j
      const int u0 = wid * 8;
      const short8* pa = Bp8 + (size_t)(1792 + u0 * 8 + j) * 128 + lane;
      const float* sd = sDg + (size_t)u0 * 4096 + e0 + nl;
      const float* pb = b2 + (size_t)(N1 + N2 + N3) + (size_t)u0 * 128 + 16 * j + 4 * grp;
      short8 F0 = pa[0], F1 = pa[64];
      f32x4 bv = *(const f32x4*)pb;
      float s0 = sd[0], s1 = sd[16], s2 = sd[32], s3 = sd[48];
#pragma unroll
      for (int t = 0; t < 8; ++t) {
        short8 f0 = F0, f1 = F1; f32x4 b = bv;
        float c0 = s0, c1 = s1, c2 = s2, c3 = s3;
        if (t < 7) {
          pa += 1024; sd += 4096; pb += 128;
          F0 = pa[0]; F1 = pa[64]; bv = *(const f32x4*)pb;
          s0 = sd[0]; s1 = sd[16]; s2 = sd[32]; s3 = sd[48];
        }
        f32x4 tt;
        tt = MFMA(f0, hL0, b); tt = MFMA(f1, hH0, tt); aD0 += c0 * tt;
        tt = MFMA(f0, hL1, b); tt = MFMA(f1, hH1, tt); aD1 += c1 * tt;
        tt = MFMA(f0, hL2, b); tt = MFMA(f1, hH2, tt); aD2 += c2 * tt;
        tt = MFMA(f0, hL3, b); tt = MFMA(f1, hH3, tt); aD3 += c3 * tt;
      }
    }
    // epilogue: 8->4 wave reduce, 4-sum, direct store (exclusive writer)
    {
      float* bw = &buf[(wid & 3) * 2112];
      if (wid >= 4) {
#pragma unroll
        for (int r = 0; r < 4; ++r) {
          bw[nl * 33 + grp * 4 + r]             = aA0[r];
          bw[(16 + nl) * 33 + grp * 4 + r]      = aA1[r];
          bw[(32 + nl) * 33 + grp * 4 + r]      = aA2[r];
          bw[(48 + nl) * 33 + grp * 4 + r]      = aA3[r];
          bw[nl * 33 + 16 + grp * 4 + r]        = aD0[r];
          bw[(16 + nl) * 33 + 16 + grp * 4 + r] = aD1[r];
          bw[(32 + nl) * 33 + 16 + grp * 4 + r] = aD2[r];
          bw[(48 + nl) * 33 + 16 + grp * 4 + r] = aD3[r];
        }
      }
      __syncthreads();
      if (wid < 4) {
#pragma unroll
        for (int r = 0; r < 4; ++r) {
          bw[nl * 33 + grp * 4 + r]             += aA0[r];
          bw[(16 + nl) * 33 + grp * 4 + r]      += aA1[r];
          bw[(32 + nl) * 33 + grp * 4 + r]      += aA2[r];
          bw[(48 + nl) * 33 + grp * 4 + r]      += aA3[r];
          bw[nl * 33 + 16 + grp * 4 + r]        += aD0[r];
          bw[(16 + nl) * 33 + 16 + grp * 4 + r] += aD1[r];
          bw[(32 + nl) * 33 + 16 + grp * 4 + r] += aD2[r];
          bw[(48 + nl) * 33 + 16 + grp * 4 + r] += aD3[r];
        }
      }
      __syncthreads();
#pragma unroll
      for (int it = 0; it < 2; ++it) {
        const int p = tid + it * 512;
        const int e = p >> 4, w = p & 15;
        float ta = buf[e * 33 + w] + buf[2112 + e * 33 + w] +
                   buf[4224 + e * 33 + w] + buf[6336 + e * 33 + w];
        float td = buf[e * 33 + 16 + w] + buf[2112 + e * 33 + 16 + w] +
                   buf[4224 + e * 33 + 16 + w] + buf[6336 + e * 33 + 16 + w];
        out[(size_t)(e0 + e) * 320 + 16 * j + w] = d2T[e0 + e] * ta + td + bias[16 * j + w];
      }
    }
  } else {
    // ================= BC =================
    const int idx = bid - 512;
    const int xcd = idx & 7;
    const int jc = xcd & 3;
    const int tile = ((idx >> 3) << 1) | (xcd >> 2);
    const int e0 = tile * 32;
    short8 gL0, gH0, gL1, gH1;
    LOADH(0, gL0, gH0);
    LOADH(1, gL1, gH1);

    f32x4 aB0 = Zv, aB1 = Zv;
    f32x4 c00 = Zv, c01 = Zv, c02 = Zv, c10 = Zv, c11 = Zv, c12 = Zv;

    {   // phase B: u in [wid*16,+16), nt = 1024 + u*4 + jc
      const int u0 = wid * 16;
      const short8* pa = Bp8 + (size_t)(1024 + u0 * 4 + jc) * 128 + lane;
      const float* sb = sBg + (size_t)u0 * 4096 + e0 + nl;
      const float* pb = b2 + (size_t)N1 + (size_t)u0 * 64 + 16 * jc + 4 * grp;
      short8 F0 = pa[0], F1 = pa[64];
      f32x4 bv = *(const f32x4*)pb;
      float s0 = sb[0], s1 = sb[16];
#pragma unroll
      for (int t = 0; t < 16; ++t) {
        short8 f0 = F0, f1 = F1; f32x4 b = bv;
        float c0 = s0, c1 = s1;
        if (t < 15) {
          pa += 512; sb += 4096; pb += 64;
          F0 = pa[0]; F1 = pa[64]; bv = *(const f32x4*)pb;
          s0 = sb[0]; s1 = sb[16];
        }
        f32x4 tt;
        tt = MFMA(f0, gL0, b); tt = MFMA(f1, gH0, tt); aB0 += c0 * tt;
        tt = MFMA(f0, gL1, b); tt = MFMA(f1, gH1, tt); aB1 += c1 * tt;
      }
    }
    {   // phase C: u in [wid*8,+8), nt = 1536 + u*4 + jc
      const int u0 = wid * 8;
      const short8* pa = Bp8 + (size_t)(1536 + u0 * 4 + jc) * 128 + lane;
      const float* sc = sCg + (size_t)(3 * u0) * 4096 + e0 + nl;
      const float* pb = b2 + (size_t)(N1 + N2) + (size_t)u0 * 64 + 16 * jc + 4 * grp;
      short8 F0 = pa[0], F1 = pa[64];
      f32x4 bv = *(const f32x4*)pb;
      float s00 = sc[0], s01 = sc[16];
      float s10 = sc[4096], s11 = sc[4096 + 16];
      float s20 = sc[8192], s21 = sc[8192 + 16];
#pragma unroll
      for (int t = 0; t < 8; ++t) {
        short8 f0 = F0, f1 = F1; f32x4 b = bv;
        float d00 = s00, d01 = s01, d10 = s10, d11 = s11, d20 = s20, d21 = s21;
        if (t < 7) {
          pa += 512; sc += 12288; pb += 64;
          F0 = pa[0]; F1 = pa[64]; bv = *(const f32x4*)pb;
          s00 = sc[0]; s01 = sc[16];
          s10 = sc[4096]; s11 = sc[4096 + 16];
          s20 = sc[8192]; s21 = sc[8192 + 16];
        }
        f32x4 t0 = MFMA(f0, gL0, b); t0 = MFMA(f1, gH0, t0);
        f32x4 t1 = MFMA(f0, gL1, b); t1 = MFMA(f1, gH1, t1);
        c00 += d00 * t0; c01 += d10 * t0; c02 += d20 * t0;
        c10 += d01 * t1; c11 += d11 * t1; c12 += d21 * t1;
      }
    }
    // epilogue: [4][32][65] slots {b, c0, c1, c2}
    {
      float* bw = &buf[(wid & 3) * 2080];
      if (wid >= 4) {
#pragma unroll
        for (int r = 0; r < 4; ++r) {
          const int w1 = grp * 4 + r;
          bw[nl * 65 + w1]             = aB0[r];
          bw[(16 + nl) * 65 + w1]      = aB1[r];
          bw[nl * 65 + 16 + w1]        = c00[r];
          bw[nl * 65 + 32 + w1]        = c01[r];
          bw[nl * 65 + 48 + w1]        = c02[r];
          bw[(16 + nl) * 65 + 16 + w1] = c10[r];
          bw[(16 + nl) * 65 + 32 + w1] = c11[r];
          bw[(16 + nl) * 65 + 48 + w1] = c12[r];
        }
      }
      __syncthreads();
      if (wid < 4) {
#pragma unroll
        for (int r = 0; r < 4; ++r) {
          const int w1 = grp * 4 + r;
          bw[nl * 65 + w1]             += aB0[r];
          bw[(16 + nl) * 65 + w1]      += aB1[r];
          bw[nl * 65 + 16 + w1]        += c00[r];
          bw[nl * 65 + 32 + w1]        += c01[r];
          bw[nl * 65 + 48 + w1]        += c02[r];
          bw[(16 + nl) * 65 + 16 + w1] += c10[r];
          bw[(16 + nl) * 65 + 32 + w1] += c11[r];
          bw[(16 + nl) * 65 + 48 + w1] += c12[r];
        }
      }
      __syncthreads();
#pragma unroll
      for (int it = 0; it < 3; ++it) {
        const int p = tid + it * 512;
        const int e = p / 48, rem = p % 48;
        const int w1 = rem / 3, i = rem % 3;
        float tb = buf[e * 65 + w1] + buf[2080 + e * 65 + w1] +
                   buf[4160 + e * 65 + w1] + buf[6240 + e * 65 + w1];
        const int co = 16 + i * 16 + w1;
        float tc = buf[e * 65 + co] + buf[2080 + e * 65 + co] +
                   buf[4160 + e * 65 + co] + buf[6240 + e * 65 + co];
        out[(size_t)(e0 + e) * 320 + 128 + (size_t)(16 * jc + w1) * 3 + i] =
            tb * d2T[(1 + i) * 4096 + e0 + e] + tc;
      }
    }
  }
}

extern "C" void kernel_launch(void* const* d_in, const int* in_sizes, int n_in,
                              void* d_out, int out_size, void* d_ws, size_t ws_size,
                              hipStream_t stream) {
  const float* d1   = (const float*)d_in[0];
  const float* d2   = (const float*)d_in[1];
  const float* wgt  = (const float*)d_in[2];
  const float* W0   = (const float*)d_in[3];
  const float* b0   = (const float*)d_in[4];
  const float* W1   = (const float*)d_in[5];
  const float* b1   = (const float*)d_in[6];
  const float* W2   = (const float*)d_in[7];
  const float* b2   = (const float*)d_in[8];
  const float* bias = (const float*)d_in[9];
  float* out = (float*)d_out;

  char* ws = (char*)d_ws;
  float* H           = (float*)(ws);                         // 1 MiB
  unsigned short* Bp = (unsigned short*)(ws + (1u << 20));   // 4.72 MB
  float* sBg         = (float*)(ws + (8u << 20));            // 2 MB  [128][4096] s1
  float* sDg         = (float*)(ws + (10u << 20));           // 1 MB  [64][4096]  ISQ3*dot12
  float* sCg         = (float*)(ws + (11u << 20));           // 3 MB  [192][4096] v1_i*s2
  float* d2T         = (float*)(ws + (14u << 20));           // 64 KB [4][4096]

  k_prep<<<1440, 256, 0, stream>>>(wgt, W0, b0, W1, b1, W2, d1, d2,
                                   H, Bp, sBg, sDg, sCg, d2T);
  k_main<<<1024, 512, 0, stream>>>(sBg, sDg, sCg, d2T, H, Bp, b2, bias, out);
}

// Round 11
// 65.073 us; speedup vs baseline: 1.2184x; 1.0544x over previous
//
#include <hip/hip_runtime.h>
#include <hip/hip_bf16.h>

typedef __attribute__((ext_vector_type(8))) short short8;   // bf16x8 MFMA frag
typedef __attribute__((ext_vector_type(4))) float f32x4;
typedef __attribute__((ext_vector_type(4))) unsigned uint4v;

constexpr int N1 = 16384, N2 = 8192, N3 = 4096;
constexpr int WN = 36864;
constexpr float ISQ3 = 0.57735026918962576451f;

__device__ __forceinline__ unsigned short f2bf(float f) {
  unsigned u = __builtin_bit_cast(unsigned, f);
  u += 0x7fffu + ((u >> 16) & 1u);   // RNE
  return (unsigned short)(u >> 16);
}

__device__ __forceinline__ unsigned pkbf(float a, float b) {
  unsigned r;
  asm("v_cvt_pk_bf16_f32 %0, %1, %2" : "=v"(r) : "v"(a), "v"(b));
  return r;
}

#define MFMA(a, b, c) __builtin_amdgcn_mfma_f32_16x16x32_bf16((a), (b), (c), 0, 0, 0)

// two f32x4 -> one bf16x8 frag
#define CVT8(X0, X1, G) do { uint4v w_;                                       \
    w_[0] = pkbf(X0[0], X0[1]); w_[1] = pkbf(X0[2], X0[3]);                   \
    w_[2] = pkbf(X1[0], X1[1]); w_[3] = pkbf(X1[2], X1[3]);                   \
    G = __builtin_bit_cast(short8, w_); } while (0)

// H frag loader: rows e0+16*EF+nl, k = grp*8.. (kh0) and 32+grp*8.. (kh1)
#define LOADH(EF, LO, HI) do {                                                \
    const float* hp_ = H + (size_t)(e0 + 16 * (EF) + nl) * 64 + grp * 8;      \
    f32x4 x0_ = *(const f32x4*)hp_,        x1_ = *(const f32x4*)(hp_ + 4);    \
    f32x4 x2_ = *(const f32x4*)(hp_ + 32), x3_ = *(const f32x4*)(hp_ + 36);   \
    CVT8(x0_, x1_, LO); CVT8(x2_, x3_, HI); } while (0)

// ---------------- prep: [0,288) W2->Bp (LDS transpose, coalesced) | [288,1312) MLP | [1312,1440) scales
__global__ __launch_bounds__(256)
void k_prep(const float* __restrict__ wgt, const float* __restrict__ W0,
            const float* __restrict__ b0, const float* __restrict__ W1,
            const float* __restrict__ b1, const float* __restrict__ W2,
            const float* __restrict__ d1, const float* __restrict__ d2,
            float* __restrict__ H, unsigned short* __restrict__ Bp,
            float* __restrict__ sBg, float* __restrict__ sDg,
            float* __restrict__ sCg, float* __restrict__ d2T) {
  __shared__ __align__(16) float shm[10400];
  const int bid = blockIdx.x;
  const int tid = threadIdx.x;

  if (bid < 288) {
    // ---- W2 -> Bp: block handles n-chunk [n0, n0+128), all 64 k-rows.
    const int n0 = bid * 128;
#pragma unroll
    for (int q = 0; q < 8; ++q) {
      const int flat = tid + q * 256;       // f32x4 units, 0..2047
      const int row = flat >> 5, c4 = flat & 31;
      *(f32x4*)&shm[row * 132 + c4 * 4] =
          *(const f32x4*)(W2 + (size_t)row * WN + n0 + c4 * 4);
    }
    __syncthreads();
#pragma unroll
    for (int q = 0; q < 4; ++q) {
      const int p = tid + q * 256;          // 0..1023
      const int ntl = p >> 7, kh = (p >> 6) & 1, lane2 = p & 63;
      const int k0 = kh * 32 + (lane2 >> 4) * 8;
      const int col = ntl * 16 + (lane2 & 15);
      short8 v;
#pragma unroll
      for (int qq = 0; qq < 8; ++qq) v[qq] = (short)f2bf(shm[(k0 + qq) * 132 + col]);
      *(short8*)(Bp + ((size_t)(n0 * 8 + p)) * 8) = v;
    }
  } else if (bid < 1312) {
    // ---- MLP: H = relu(relu(weight@W0+b0)@W1+b1)
    float* h0s = shm;
    const int r = tid >> 6, jj = tid & 63;
    const int e = (bid - 288) * 4 + r;
    float a = b0[jj];
#pragma unroll
    for (int i = 0; i < 16; ++i) a = fmaf(wgt[e * 16 + i], W0[i * 64 + jj], a);
    h0s[r * 64 + jj] = fmaxf(a, 0.f);
    __syncthreads();
    float a1 = b1[jj];
#pragma unroll
    for (int i = 0; i < 64; ++i) a1 = fmaf(h0s[r * 64 + i], W1[i * 64 + jj], a1);
    H[e * 64 + jj] = fmaxf(a1, 0.f);
  } else {
    // ---- scales: sBg[u][e]=s1, sDg[u][e]=ISQ3*dot12, sCg[3u+i][e]=v1_i*s2, d2T[c][e]
    float* d1s = shm;            // [32][321]
    float* d2s = shm + 10272;    // [32][4]
    const int e0 = (bid - 1312) * 32;
    for (int x = tid; x < 32 * 320; x += 256) {
      int e = x / 320, c = x % 320;
      d1s[e * 321 + c] = d1[(size_t)(e0 + e) * 320 + c];
    }
    if (tid < 128) d2s[tid] = d2[(size_t)e0 * 4 + tid];
    __syncthreads();
    const int e = tid & 31;
    const float s2 = d2s[e * 4 + 0];
    const float w1 = d2s[e * 4 + 1], w2 = d2s[e * 4 + 2], w3 = d2s[e * 4 + 3];
    for (int row = 128 + (tid >> 5); row < 516; row += 8) {
      float v; float* dst;
      if (row < 256)      { v = d1s[e * 321 + (row - 128)];            dst = sBg + (size_t)(row - 128) * 4096; }
      else if (row < 320) { int u = row - 256;
        v = ISQ3 * (d1s[e * 321 + 128 + 3 * u] * w1 + d1s[e * 321 + 129 + 3 * u] * w2 +
                    d1s[e * 321 + 130 + 3 * u] * w3);                  dst = sDg + (size_t)u * 4096; }
      else if (row < 512) { v = d1s[e * 321 + 128 + (row - 320)] * s2; dst = sCg + (size_t)(row - 320) * 4096; }
      else                { v = d2s[e * 4 + (row - 512)];              dst = d2T + (size_t)(row - 512) * 4096; }
      dst[e0 + e] = v;
    }
  }
}

// ---------------- k_main: exclusive-writer columns, b2 via MFMA C-init, depth-3 prefetch rings ----------------
// bid [0,512): AD — e-tile 64, j = bid&7 (XCD-pinned). Writes out0 cols [16j,16j+16).
// bid [512,1024): BC — e-tile 32, jc = xcd&3. Writes out1 w1 cols [16jc,16jc+16) (x3 i).
// 256 threads = 4 waves; each wave covers a u-quarter; depth-3 ring; 4-wave LDS reduce.
__global__ __launch_bounds__(256, 3)
void k_main(const float* __restrict__ sBg, const float* __restrict__ sDg,
            const float* __restrict__ sCg, const float* __restrict__ d2T,
            const float* __restrict__ H, const unsigned short* __restrict__ Bp,
            const float* __restrict__ b2, const float* __restrict__ bias,
            float* __restrict__ out) {
  __shared__ __align__(16) float buf[8448];   // 33.8 KB: AD [4][64][33], BC [4][32][65]
  const int bid = blockIdx.x, tid = threadIdx.x;
  const int wid = tid >> 6, lane = tid & 63;
  const int nl = lane & 15, grp = lane >> 4;
  const short8* Bp8 = (const short8*)Bp;
  const f32x4 Zv = {0.f, 0.f, 0.f, 0.f};

  if (bid < 512) {
    // ================= AD =================
    const int j = bid & 7;
    const int e0 = (bid >> 3) * 64;
    short8 hL0, hH0, hL1, hH1, hL2, hH2, hL3, hH3;
    LOADH(0, hL0, hH0);
    LOADH(1, hL1, hH1);
    LOADH(2, hL2, hH2);
    LOADH(3, hL3, hH3);

    f32x4 aA0 = Zv, aA1 = Zv, aA2 = Zv, aA3 = Zv;
    f32x4 aD0 = Zv, aD1 = Zv, aD2 = Zv, aD3 = Zv;

    {   // phase A: u in [wid*32, +32), nt = u*8 + j
      const int u0 = wid * 32;
      const short8* pa = Bp8 + (size_t)(u0 * 8 + j) * 128 + lane;
      const float* sb = sBg + (size_t)u0 * 4096 + e0 + nl;
      const float* pb = b2 + (size_t)u0 * 128 + 16 * j + 4 * grp;
      short8 Fa[3], Fb[3]; f32x4 Bv[3];
      float S0[3], S1[3], S2[3], S3[3];
#pragma unroll
      for (int q = 0; q < 3; ++q) {
        Fa[q] = pa[0]; Fb[q] = pa[64];
        Bv[q] = *(const f32x4*)pb;
        S0[q] = sb[0]; S1[q] = sb[16]; S2[q] = sb[32]; S3[q] = sb[48];
        pa += 1024; sb += 4096; pb += 128;
      }
#pragma unroll
      for (int t = 0; t < 32; ++t) {
        const int s = t % 3;
        short8 f0 = Fa[s], f1 = Fb[s]; f32x4 b = Bv[s];
        float c0 = S0[s], c1 = S1[s], c2 = S2[s], c3 = S3[s];
        if (t < 29) {
          Fa[s] = pa[0]; Fb[s] = pa[64];
          Bv[s] = *(const f32x4*)pb;
          S0[s] = sb[0]; S1[s] = sb[16]; S2[s] = sb[32]; S3[s] = sb[48];
          pa += 1024; sb += 4096; pb += 128;
        }
        f32x4 tt;
        tt = MFMA(f0, hL0, b); tt = MFMA(f1, hH0, tt); aA0 += c0 * tt;
        tt = MFMA(f0, hL1, b); tt = MFMA(f1, hH1, tt); aA1 += c1 * tt;
        tt = MFMA(f0, hL2, b); tt = MFMA(f1, hH2, tt); aA2 += c2 * tt;
        tt = MFMA(f0, hL3, b); tt = MFMA(f1, hH3, tt); aA3 += c3 * tt;
      }
    }
    {   // phase D: u in [wid*16, +16), nt = 1792 + u*8 + j
      const int u0 = wid * 16;
      const short8* pa = Bp8 + (size_t)(1792 + u0 * 8 + j) * 128 + lane;
      const float* sd = sDg + (size_t)u0 * 4096 + e0 + nl;
      const float* pb = b2 + (size_t)(N1 + N2 + N3) + (size_t)u0 * 128 + 16 * j + 4 * grp;
      short8 Fa[3], Fb[3]; f32x4 Bv[3];
      float S0[3], S1[3], S2[3], S3[3];
#pragma unroll
      for (int q = 0; q < 3; ++q) {
        Fa[q] = pa[0]; Fb[q] = pa[64];
        Bv[q] = *(const f32x4*)pb;
        S0[q] = sd[0]; S1[q] = sd[16]; S2[q] = sd[32]; S3[q] = sd[48];
        pa += 1024; sd += 4096; pb += 128;
      }
#pragma unroll
      for (int t = 0; t < 16; ++t) {
        const int s = t % 3;
        short8 f0 = Fa[s], f1 = Fb[s]; f32x4 b = Bv[s];
        float c0 = S0[s], c1 = S1[s], c2 = S2[s], c3 = S3[s];
        if (t < 13) {
          Fa[s] = pa[0]; Fb[s] = pa[64];
          Bv[s] = *(const f32x4*)pb;
          S0[s] = sd[0]; S1[s] = sd[16]; S2[s] = sd[32]; S3[s] = sd[48];
          pa += 1024; sd += 4096; pb += 128;
        }
        f32x4 tt;
        tt = MFMA(f0, hL0, b); tt = MFMA(f1, hH0, tt); aD0 += c0 * tt;
        tt = MFMA(f0, hL1, b); tt = MFMA(f1, hH1, tt); aD1 += c1 * tt;
        tt = MFMA(f0, hL2, b); tt = MFMA(f1, hH2, tt); aD2 += c2 * tt;
        tt = MFMA(f0, hL3, b); tt = MFMA(f1, hH3, tt); aD3 += c3 * tt;
      }
    }
    // epilogue: 4-wave store, sum, direct write (exclusive writer)
    {
      float* bw = &buf[wid * 2112];
#pragma unroll
      for (int r = 0; r < 4; ++r) {
        bw[nl * 33 + grp * 4 + r]             = aA0[r];
        bw[(16 + nl) * 33 + grp * 4 + r]      = aA1[r];
        bw[(32 + nl) * 33 + grp * 4 + r]      = aA2[r];
        bw[(48 + nl) * 33 + grp * 4 + r]      = aA3[r];
        bw[nl * 33 + 16 + grp * 4 + r]        = aD0[r];
        bw[(16 + nl) * 33 + 16 + grp * 4 + r] = aD1[r];
        bw[(32 + nl) * 33 + 16 + grp * 4 + r] = aD2[r];
        bw[(48 + nl) * 33 + 16 + grp * 4 + r] = aD3[r];
      }
      __syncthreads();
#pragma unroll
      for (int it = 0; it < 4; ++it) {
        const int p = tid + it * 256;
        const int e = p >> 4, w = p & 15;
        float ta = buf[e * 33 + w] + buf[2112 + e * 33 + w] +
                   buf[4224 + e * 33 + w] + buf[6336 + e * 33 + w];
        float td = buf[e * 33 + 16 + w] + buf[2112 + e * 33 + 16 + w] +
                   buf[4224 + e * 33 + 16 + w] + buf[6336 + e * 33 + 16 + w];
        out[(size_t)(e0 + e) * 320 + 16 * j + w] = d2T[e0 + e] * ta + td + bias[16 * j + w];
      }
    }
  } else {
    // ================= BC =================
    const int idx = bid - 512;
    const int xcd = idx & 7;
    const int jc = xcd & 3;
    const int tile = ((idx >> 3) << 1) | (xcd >> 2);
    const int e0 = tile * 32;
    short8 gL0, gH0, gL1, gH1;
    LOADH(0, gL0, gH0);
    LOADH(1, gL1, gH1);

    f32x4 aB0 = Zv, aB1 = Zv;
    f32x4 c00 = Zv, c01 = Zv, c02 = Zv, c10 = Zv, c11 = Zv, c12 = Zv;

    {   // phase B: u in [wid*32,+32), nt = 1024 + u*4 + jc
      const int u0 = wid * 32;
      const short8* pa = Bp8 + (size_t)(1024 + u0 * 4 + jc) * 128 + lane;
      const float* sb = sBg + (size_t)u0 * 4096 + e0 + nl;
      const float* pb = b2 + (size_t)N1 + (size_t)u0 * 64 + 16 * jc + 4 * grp;
      short8 Fa[3], Fb[3]; f32x4 Bv[3];
      float S0[3], S1[3];
#pragma unroll
      for (int q = 0; q < 3; ++q) {
        Fa[q] = pa[0]; Fb[q] = pa[64];
        Bv[q] = *(const f32x4*)pb;
        S0[q] = sb[0]; S1[q] = sb[16];
        pa += 512; sb += 4096; pb += 64;
      }
#pragma unroll
      for (int t = 0; t < 32; ++t) {
        const int s = t % 3;
        short8 f0 = Fa[s], f1 = Fb[s]; f32x4 b = Bv[s];
        float c0 = S0[s], c1 = S1[s];
        if (t < 29) {
          Fa[s] = pa[0]; Fb[s] = pa[64];
          Bv[s] = *(const f32x4*)pb;
          S0[s] = sb[0]; S1[s] = sb[16];
          pa += 512; sb += 4096; pb += 64;
        }
        f32x4 tt;
        tt = MFMA(f0, gL0, b); tt = MFMA(f1, gH0, tt); aB0 += c0 * tt;
        tt = MFMA(f0, gL1, b); tt = MFMA(f1, gH1, tt); aB1 += c1 * tt;
      }
    }
    {   // phase C: u in [wid*16,+16), nt = 1536 + u*4 + jc
      const int u0 = wid * 16;
      const short8* pa = Bp8 + (size_t)(1536 + u0 * 4 + jc) * 128 + lane;
      const float* sc = sCg + (size_t)(3 * u0) * 4096 + e0 + nl;
      const float* pb = b2 + (size_t)(N1 + N2) + (size_t)u0 * 64 + 16 * jc + 4 * grp;
      short8 Fa[3], Fb[3]; f32x4 Bv[3];
      float S00[3], S01[3], S10[3], S11[3], S20[3], S21[3];
#pragma unroll
      for (int q = 0; q < 3; ++q) {
        Fa[q] = pa[0]; Fb[q] = pa[64];
        Bv[q] = *(const f32x4*)pb;
        S00[q] = sc[0]; S01[q] = sc[16];
        S10[q] = sc[4096]; S11[q] = sc[4096 + 16];
        S20[q] = sc[8192]; S21[q] = sc[8192 + 16];
        pa += 512; sc += 12288; pb += 64;
      }
#pragma unroll
      for (int t = 0; t < 16; ++t) {
        const int s = t % 3;
        short8 f0 = Fa[s], f1 = Fb[s]; f32x4 b = Bv[s];
        float d00 = S00[s], d01 = S01[s], d10 = S10[s], d11 = S11[s], d20 = S20[s], d21 = S21[s];
        if (t < 13) {
          Fa[s] = pa[0]; Fb[s] = pa[64];
          Bv[s] = *(const f32x4*)pb;
          S00[s] = sc[0]; S01[s] = sc[16];
          S10[s] = sc[4096]; S11[s] = sc[4096 + 16];
          S20[s] = sc[8192]; S21[s] = sc[8192 + 16];
          pa += 512; sc += 12288; pb += 64;
        }
        f32x4 t0 = MFMA(f0, gL0, b); t0 = MFMA(f1, gH0, t0);
        f32x4 t1 = MFMA(f0, gL1, b); t1 = MFMA(f1, gH1, t1);
        c00 += d00 * t0; c01 += d10 * t0; c02 += d20 * t0;
        c10 += d01 * t1; c11 += d11 * t1; c12 += d21 * t1;
      }
    }
    // epilogue: 4-wave store, sum, direct write; slots {b, c0, c1, c2}
    {
      float* bw = &buf[wid * 2080];
#pragma unroll
      for (int r = 0; r < 4; ++r) {
        const int w1 = grp * 4 + r;
        bw[nl * 65 + w1]             = aB0[r];
        bw[(16 + nl) * 65 + w1]      = aB1[r];
        bw[nl * 65 + 16 + w1]        = c00[r];
        bw[nl * 65 + 32 + w1]        = c01[r];
        bw[nl * 65 + 48 + w1]        = c02[r];
        bw[(16 + nl) * 65 + 16 + w1] = c10[r];
        bw[(16 + nl) * 65 + 32 + w1] = c11[r];
        bw[(16 + nl) * 65 + 48 + w1] = c12[r];
      }
      __syncthreads();
#pragma unroll
      for (int it = 0; it < 6; ++it) {
        const int p = tid + it * 256;
        const int e = p / 48, rem = p % 48;
        const int w1 = rem / 3, i = rem % 3;
        float tb = buf[e * 65 + w1] + buf[2080 + e * 65 + w1] +
                   buf[4160 + e * 65 + w1] + buf[6240 + e * 65 + w1];
        const int co = 16 + i * 16 + w1;
        float tc = buf[e * 65 + co] + buf[2080 + e * 65 + co] +
                   buf[4160 + e * 65 + co] + buf[6240 + e * 65 + co];
        out[(size_t)(e0 + e) * 320 + 128 + (size_t)(16 * jc + w1) * 3 + i] =
            tb * d2T[(1 + i) * 4096 + e0 + e] + tc;
      }
    }
  }
}

extern "C" void kernel_launch(void* const* d_in, const int* in_sizes, int n_in,
                              void* d_out, int out_size, void* d_ws, size_t ws_size,
                              hipStream_t stream) {
  const float* d1   = (const float*)d_in[0];
  const float* d2   = (const float*)d_in[1];
  const float* wgt  = (const float*)d_in[2];
  const float* W0   = (const float*)d_in[3];
  const float* b0   = (const float*)d_in[4];
  const float* W1   = (const float*)d_in[5];
  const float* b1   = (const float*)d_in[6];
  const float* W2   = (const float*)d_in[7];
  const float* b2   = (const float*)d_in[8];
  const float* bias = (const float*)d_in[9];
  float* out = (float*)d_out;

  char* ws = (char*)d_ws;
  float* H           = (float*)(ws);                         // 1 MiB
  unsigned short* Bp = (unsigned short*)(ws + (1u << 20));   // 4.72 MB
  float* sBg         = (float*)(ws + (8u << 20));            // 2 MB  [128][4096] s1
  float* sDg         = (float*)(ws + (10u << 20));           // 1 MB  [64][4096]  ISQ3*dot12
  float* sCg         = (float*)(ws + (11u << 20));           // 3 MB  [192][4096] v1_i*s2
  float* d2T         = (float*)(ws + (14u << 20));           // 64 KB [4][4096]

  k_prep<<<1440, 256, 0, stream>>>(wgt, W0, b0, W1, b1, W2, d1, d2,
                                   H, Bp, sBg, sDg, sCg, d2T);
  k_main<<<1024, 256, 0, stream>>>(sBg, sDg, sCg, d2T, H, Bp, b2, bias, out);
}